// Round 16
// baseline (142.013 us; speedup 1.0000x reference)
//
#include <hip/hip_runtime.h>

typedef __attribute__((ext_vector_type(8))) _Float16 f16x8;
typedef __attribute__((ext_vector_type(4))) float f4v;
typedef __attribute__((ext_vector_type(16))) float f16v;
typedef __attribute__((ext_vector_type(8))) unsigned short us8;
typedef __attribute__((ext_vector_type(4))) unsigned short us4;
typedef unsigned short u16;

__device__ __forceinline__ u16 h2b(_Float16 h) { return __builtin_bit_cast(u16, h); }
__device__ __forceinline__ float b2f(u16 b) {
    return (float)__builtin_bit_cast(_Float16, b);
}

// Raw barrier: drain LDS ops only; leave prefetch global loads in flight.
#define BAR() do { asm volatile("s_waitcnt lgkmcnt(0)" ::: "memory"); \
                   __builtin_amdgcn_s_barrier(); } while (0)

// ---- W2 partials (fold fused): w2p[es][d][j] = sum_e adf[d][es*100+e]*d1w --
__global__ void k_w2p(const float* __restrict__ ad, const float* __restrict__ d1w,
                      float* __restrict__ w2p) {
    int i = blockIdx.x * 256 + threadIdx.x;       // 128 d x 400 j
    if (i >= 51200) return;
    int es = blockIdx.y;
    int d = i / 400, j = i % 400;
    float acc = 0.f;
    if (d < 100) {
        const float* a0 = ad + d * 400 + es * 100;          // + k*40000
        const float* wr = d1w + (es * 100) * 400 + j;
        #pragma unroll 4
        for (int e = 0; e < 100; ++e) {
            float av = a0[e] + a0[40000 + e] + a0[80000 + e] + a0[120000 + e];
            acc += av * wr[e * 400];
        }
    }
    w2p[es * 51200 + i] = acc;
}

// ---- reduce partials, pack to fp16 MFMA B-fragments [25 nt][4 ks][64][8] --
__global__ void k_w2r(const float* __restrict__ w2p, u16* __restrict__ w2f) {
    int i = blockIdx.x * 256 + threadIdx.x;
    if (i >= 51200) return;
    float acc = w2p[i] + w2p[51200 + i] + w2p[102400 + i] + w2p[153600 + i];
    int d = i / 400, j = i % 400;
    int idx = ((j >> 4) * 4 + (d >> 5)) * 512 + (((d >> 3) & 3) * 16 + (j & 15)) * 8 + (d & 7);
    w2f[idx] = h2b((_Float16)acc);
}

// ---- W prep: fp16 hi/lo tiles [3 m][13 ks][2 hl][128 n][32 k], x-swizzled -
__global__ void k_wprep(const float* __restrict__ ak, u16* __restrict__ wsp) {
    int i = blockIdx.x * 256 + threadIdx.x;       // 3*13*4096 = 159744
    if (i >= 159744) return;
    int k = i & 31, n = (i >> 5) & 127;
    int xx = i >> 12;                             // m*13 + ks
    int ks = xx % 13, m = xx / 13;
    int gk = ks * 32 + k;
    float v = (n < 100 && gk < 400) ? ak[m * 40000 + gk * 100 + n] : 0.f;
    _Float16 hb = (_Float16)v;
    _Float16 lb = (_Float16)(v - (float)hb);
    long base = (long)xx * 8192;
    int pos = n * 32 + ((((k >> 3) ^ (n & 3)) << 3) | (k & 7));
    wsp[base + pos] = h2b(hb);
    wsp[base + 4096 + pos] = h2b(lb);
}

// ---------------- QKV via fp16 MFMA: merged Q+K+V, 128 rows, 8 waves -------
// grid 256, block 512. x loaded & hi/lo-split ONCE per row block.
__global__ __launch_bounds__(512) void k_gemm_qkv(
    const float* __restrict__ x, const u16* __restrict__ wsp,
    u16* __restrict__ QH, u16* __restrict__ KH, u16* __restrict__ VT) {
    __shared__ __align__(16) u16 smem[49152];     // 2 x 48KB; epi aliases

    const int tid = threadIdx.x;
    const int rowblk = blockIdx.x;
    const long row0 = (long)rowblk * 128;
    const int w = tid >> 6, l = tid & 63, g = l >> 4, c15 = l & 15;
    const int sr = tid >> 2, skc = tid & 3;       // x-stage: 128 rows x 4 chunks

    f4v aQ[8], aK[8], aV[8];
    #pragma unroll
    for (int nt = 0; nt < 8; ++nt) {
        aQ[nt] = (f4v){0.f, 0.f, 0.f, 0.f};
        aK[nt] = (f4v){0.f, 0.f, 0.f, 0.f};
        aV[nt] = (f4v){0.f, 0.f, 0.f, 0.f};
    }

    const u16* wq  = wsp;                          // m0 hi
    const u16* wkh = wsp + 106496;                 // m1 hi (13*8192)
    const u16* wkl = wsp + 110592;                 // m1 lo
    const u16* wv  = wsp + 212992;                 // m2 hi (26*8192)

    float4 xr0, xr1;
    us8 wr[4];
    const int xpos = sr * 32 + ((skc * 8) ^ ((sr & 3) << 3));

    // ---- prologue: load ks=0, stage into buf0, load ks=1
    {
        const float* xp = x + (row0 + sr) * 400 + skc * 8;
        xr0 = *(const float4*)xp;
        xr1 = *(const float4*)(xp + 4);
        wr[0] = *(const us8*)&wq [(long)tid * 8];
        wr[1] = *(const us8*)&wkh[(long)tid * 8];
        wr[2] = *(const us8*)&wkl[(long)tid * 8];
        wr[3] = *(const us8*)&wv [(long)tid * 8];
        float va[8] = {xr0.x, xr0.y, xr0.z, xr0.w, xr1.x, xr1.y, xr1.z, xr1.w};
        us8 hi8, lo8;
        #pragma unroll
        for (int j = 0; j < 8; ++j) {
            _Float16 h = (_Float16)va[j];
            hi8[j] = h2b(h);
            lo8[j] = h2b((_Float16)(va[j] - (float)h));
        }
        *(us8*)&smem[xpos] = hi8;
        *(us8*)&smem[4096 + xpos] = lo8;
        *(us8*)&smem[8192  + tid * 8] = wr[0];
        *(us8*)&smem[12288 + tid * 8] = wr[1];
        *(us8*)&smem[16384 + tid * 8] = wr[2];
        *(us8*)&smem[20480 + tid * 8] = wr[3];
        const float* xp1 = x + (row0 + sr) * 400 + 32 + skc * 8;
        xr0 = *(const float4*)xp1;
        xr1 = *(const float4*)(xp1 + 4);
        wr[0] = *(const us8*)&wq [8192 + (long)tid * 8];
        wr[1] = *(const us8*)&wkh[8192 + (long)tid * 8];
        wr[2] = *(const us8*)&wkl[8192 + (long)tid * 8];
        wr[3] = *(const us8*)&wv [8192 + (long)tid * 8];
    }

    for (int ks = 0; ks < 13; ++ks) {
        BAR();
        u16* cb = smem + (ks & 1) * 24576;         // compute buf (tile ks)
        u16* sb = smem + ((ks & 1) ^ 1) * 24576;   // stage buf (tile ks+1)
        if (ks + 1 < 13) {
            float va[8] = {xr0.x, xr0.y, xr0.z, xr0.w, xr1.x, xr1.y, xr1.z, xr1.w};
            us8 hi8, lo8;
            #pragma unroll
            for (int j = 0; j < 8; ++j) {
                _Float16 h = (_Float16)va[j];
                hi8[j] = h2b(h);
                lo8[j] = h2b((_Float16)(va[j] - (float)h));
            }
            *(us8*)&sb[xpos] = hi8;
            *(us8*)&sb[4096 + xpos] = lo8;
            *(us8*)&sb[8192  + tid * 8] = wr[0];
            *(us8*)&sb[12288 + tid * 8] = wr[1];
            *(us8*)&sb[16384 + tid * 8] = wr[2];
            *(us8*)&sb[20480 + tid * 8] = wr[3];
            if (ks + 2 < 13) {
                if ((ks + 2) * 32 + skc * 8 < 400) {
                    const float* xp = x + (row0 + sr) * 400 + (ks + 2) * 32 + skc * 8;
                    xr0 = *(const float4*)xp;
                    xr1 = *(const float4*)(xp + 4);
                } else {
                    xr0 = make_float4(0.f, 0.f, 0.f, 0.f);
                    xr1 = make_float4(0.f, 0.f, 0.f, 0.f);
                }
                long wo = (long)(ks + 2) * 8192 + (long)tid * 8;
                wr[0] = *(const us8*)&wq [wo];
                wr[1] = *(const us8*)&wkh[wo];
                wr[2] = *(const us8*)&wkl[wo];
                wr[3] = *(const us8*)&wv [wo];
            }
        }
        // ---- MFMA on compute buf: 7 per nt (Q:2, K:3, V:2)
        const int arow = w * 16 + c15;
        const int axo = arow * 32 + ((g * 8) ^ ((arow & 3) << 3));
        f16x8 ah = *(const f16x8*)&cb[axo];
        f16x8 al = *(const f16x8*)&cb[4096 + axo];
        __builtin_amdgcn_s_setprio(1);
        #pragma unroll
        for (int nt = 0; nt < 8; ++nt) {
            int brow = nt * 16 + c15;
            int boff = brow * 32 + ((g * 8) ^ ((brow & 3) << 3));
            f16x8 qb = *(const f16x8*)&cb[8192 + boff];
            aQ[nt] = __builtin_amdgcn_mfma_f32_16x16x32_f16(ah, qb, aQ[nt], 0, 0, 0);
            aQ[nt] = __builtin_amdgcn_mfma_f32_16x16x32_f16(al, qb, aQ[nt], 0, 0, 0);
            f16x8 kh = *(const f16x8*)&cb[12288 + boff];
            aK[nt] = __builtin_amdgcn_mfma_f32_16x16x32_f16(ah, kh, aK[nt], 0, 0, 0);
            aK[nt] = __builtin_amdgcn_mfma_f32_16x16x32_f16(al, kh, aK[nt], 0, 0, 0);
            f16x8 kl = *(const f16x8*)&cb[16384 + boff];
            aK[nt] = __builtin_amdgcn_mfma_f32_16x16x32_f16(ah, kl, aK[nt], 0, 0, 0);
            f16x8 vb = *(const f16x8*)&cb[20480 + boff];
            aV[nt] = __builtin_amdgcn_mfma_f32_16x16x32_f16(ah, vb, aV[nt], 0, 0, 0);
            aV[nt] = __builtin_amdgcn_mfma_f32_16x16x32_f16(al, vb, aV[nt], 0, 0, 0);
        }
        __builtin_amdgcn_s_setprio(0);
    }
    BAR();
    u16* epi = smem;                               // alias (safe post-BAR)

    // ---- epilogue Q: swizzled deposit (scaled), un-swizzle to row-major
    {
        const float qs = 0.14426950408889634f;     // 0.1 * log2(e)
        #pragma unroll
        for (int nt = 0; nt < 8; ++nt) {
            #pragma unroll
            for (int r = 0; r < 4; ++r) {
                int row = w * 16 + 4 * g + r, col = nt * 16 + c15;
                epi[row * 128 + (col ^ ((row & 7) << 3))] =
                    h2b((_Float16)(aQ[nt][r] * qs));
            }
        }
        __syncthreads();
        #pragma unroll
        for (int r = 0; r < 4; ++r) {
            int u = tid + r * 512;
            int row = u >> 4, c = u & 15;
            *(us8*)&QH[(row0 + row) * 128 + c * 8] =
                *(const us8*)&epi[row * 128 + ((c * 8) ^ ((row & 7) << 3))];
        }
        __syncthreads();
    }
    // ---- epilogue K: swizzled deposit, linear dump = 2 tile images
    {
        #pragma unroll
        for (int nt = 0; nt < 8; ++nt) {
            #pragma unroll
            for (int r = 0; r < 4; ++r) {
                int row = w * 16 + 4 * g + r, col = nt * 16 + c15;
                epi[row * 128 + (col ^ ((row & 7) << 3))] = h2b((_Float16)aK[nt][r]);
            }
        }
        __syncthreads();
        u16* dst = KH + (long)rowblk * 16384;
        #pragma unroll
        for (int r = 0; r < 4; ++r) {
            int u = tid + r * 512;
            *(us8*)&dst[(long)u * 8] = *(const us8*)&epi[u * 8];
        }
        __syncthreads();
    }
    // ---- epilogue V: transposed deposit, dump 2 PACKED tile images (d<112)
    {
        const int q0 = w * 16 + 4 * g;
        const int vtile = q0 >> 6, q0w = q0 & 63;
        #pragma unroll
        for (int nt = 0; nt < 8; ++nt) {
            int d = nt * 16 + c15;
            if (d < 112) {
                us4 v4;
                #pragma unroll
                for (int r = 0; r < 4; ++r) v4[r] = h2b((_Float16)aV[nt][r]);
                *(us4*)&epi[vtile * 8192 + d * 64 + (q0w ^ ((d & 7) << 3))] = v4;
            }
        }
        __syncthreads();
        #pragma unroll
        for (int r = 0; r < 4; ++r) {
            int u = tid + r * 512;
            int vt2 = u >> 10, uu = u & 1023;
            if (uu < 896)
                *(us8*)&VT[((long)(2 * rowblk + vt2)) * 7168 + (long)uu * 8] =
                    *(const us8*)&epi[u * 8];
        }
    }
}

// ---------------- fp16 MFMA flash v16: 32x32 QK^T, key-split, 8 waves ------
// grid (16, 16, 2), block 512. Wave (qg,kh): 32 q x 32 keys per 64-key tile
// via ONE 32x32x16 MFMA chain (8 A-reads/tile vs 16). PV = 16x16x32 via
// P-LDS round-trip. Max-free softmax => key-half (O,l) additive; LDS combine.
__global__ __launch_bounds__(512) void k_flash(
    const u16* __restrict__ Qg, const u16* __restrict__ Kg,
    const u16* __restrict__ Vg, u16* __restrict__ VOI,
    float* __restrict__ ML) {
    // carve: KS[c]=c*16384  VS[c]=32768+c*14336  PS[w]=61440+w*2048
    __shared__ __align__(16) char smem[77824];

    const int tid = threadIdx.x;
    const int w = tid >> 6, l = tid & 63;
    const int l31 = l & 31, hi = l >> 5;          // 32-wide frag coords
    const int c15 = l & 15, g = (l >> 4) & 3;     // 16-wide frag coords
    const int qg = w & 3, kh = w >> 2;
    const int b = blockIdx.y, qt = blockIdx.x, half = blockIdx.z;
    const int t0 = half * 16;

    // Q B-frags (32x32x16): q = qg*32 + l31, k(d) = st*16 + hi*8 + j
    const u16* qp = Qg + ((long)b * 2048 + qt * 128 + qg * 32 + l31) * 128 + hi * 8;
    f16x8 qh[8];
    #pragma unroll
    for (int st = 0; st < 8; ++st) qh[st] = *(const f16x8*)(qp + st * 16);

    f4v O[2][7];
    #pragma unroll
    for (int h = 0; h < 2; ++h)
        #pragma unroll
        for (int i = 0; i < 7; ++i) O[h][i] = (f4v){0.f, 0.f, 0.f, 0.f};
    float lrow = 0.f;

    const char* Kb = (const char*)(Kg + (long)b * 32 * 8192);   // 16384 B/tile
    const char* Vb = (const char*)(Vg + (long)b * 32 * 7168);   // 14336 B/tile
    char* Pw = smem + 61440 + w * 2048;

    // ---- prologue: load t0 -> regs, write buf0, load t0+1 -> regs
    us8 kreg[2], vreg[2];
    #pragma unroll
    for (int r = 0; r < 2; ++r) {
        int u = tid + r * 512;
        kreg[r] = *(const us8*)(Kb + (long)t0 * 16384 + (long)u * 16);
        if (u < 896) vreg[r] = *(const us8*)(Vb + (long)t0 * 14336 + (long)u * 16);
    }
    #pragma unroll
    for (int r = 0; r < 2; ++r) {
        int u = tid + r * 512;
        *(us8*)(smem + u * 16) = kreg[r];
        if (u < 896) *(us8*)(smem + 32768 + u * 16) = vreg[r];
    }
    #pragma unroll
    for (int r = 0; r < 2; ++r) {
        int u = tid + r * 512;
        kreg[r] = *(const us8*)(Kb + (long)(t0 + 1) * 16384 + (long)u * 16);
        if (u < 896) vreg[r] = *(const us8*)(Vb + (long)(t0 + 1) * 14336 + (long)u * 16);
    }

    for (int t = t0; t < t0 + 16; ++t) {
        const int cur = (t - t0) & 1;
        BAR();   // buf[cur] writes visible; buf[cur^1] readers (t-1) done
        if (t + 1 < t0 + 16) {
            #pragma unroll
            for (int r = 0; r < 2; ++r) {
                int u = tid + r * 512;
                *(us8*)(smem + (cur ^ 1) * 16384 + u * 16) = kreg[r];
                if (u < 896)
                    *(us8*)(smem + 32768 + (cur ^ 1) * 14336 + u * 16) = vreg[r];
            }
            if (t + 2 < t0 + 16) {
                #pragma unroll
                for (int r = 0; r < 2; ++r) {
                    int u = tid + r * 512;
                    kreg[r] = *(const us8*)(Kb + (long)(t + 2) * 16384 + (long)u * 16);
                    if (u < 896)
                        vreg[r] = *(const us8*)(Vb + (long)(t + 2) * 14336 + (long)u * 16);
                }
            }
        }
        const char* Kc = smem + cur * 16384;
        const char* Vc = smem + 32768 + cur * 14336;

        // ---- S = K Q^T (32x32x16): S[key][q], key = kh*32 + (reg&3)+8(reg>>2)+4hi
        f16v S = {};
        const int key = kh * 32 + l31;            // A-frag row
        __builtin_amdgcn_s_setprio(1);
        #pragma unroll
        for (int st = 0; st < 8; ++st) {
            f16x8 kf = *(const f16x8*)(Kc + key * 256 +
                                       (((st * 2 + hi) * 16) ^ ((key & 7) << 4)));
            S = __builtin_amdgcn_mfma_f32_32x32x16_f16(kf, qh[st], S, 0, 0, 0);
        }
        __builtin_amdgcn_s_setprio(0);

        // ---- softmax numerators (Q pre-scaled by 0.1*log2e); q = l31
        float sum = 0.f;
        #pragma unroll
        for (int r = 0; r < 16; ++r) {
            float p = exp2f(S[r]);
            S[r] = p;
            sum += p;
        }
        sum += __shfl_xor(sum, 32);
        lrow += sum;

        // ---- P -> per-wave LDS [32 q][32 k]: regs 4i..4i+3 = keys 8i+{0..3}+4hi
        #pragma unroll
        for (int i = 0; i < 4; ++i) {
            uint2 pp;
            pp.x = __builtin_bit_cast(unsigned int,
                        __builtin_amdgcn_cvt_pkrtz(S[4 * i], S[4 * i + 1]));
            pp.y = __builtin_bit_cast(unsigned int,
                        __builtin_amdgcn_cvt_pkrtz(S[4 * i + 2], S[4 * i + 3]));
            *(uint2*)(Pw + l31 * 64 + ((i ^ (l31 & 3)) << 4) + hi * 8) = pp;
        }
        // ---- PV (16x16x32) over this wave's 32 keys; vf shared across q-halves
        __builtin_amdgcn_s_setprio(1);
        f16x8 pa0 = *(const f16x8*)(Pw + c15 * 64 + ((g ^ (c15 & 3)) << 4));
        f16x8 pa1 = *(const f16x8*)(Pw + (16 + c15) * 64 + ((g ^ (c15 & 3)) << 4));
        #pragma unroll
        for (int dt = 0; dt < 7; ++dt) {
            int d = dt * 16 + c15;
            f16x8 vf = *(const f16x8*)(Vc + d * 128 +
                                       ((kh * 64 + g * 16) ^ ((d & 7) << 4)));
            O[0][dt] = __builtin_amdgcn_mfma_f32_16x16x32_f16(pa0, vf, O[0][dt], 0, 0, 0);
            O[1][dt] = __builtin_amdgcn_mfma_f32_16x16x32_f16(pa1, vf, O[1][dt], 0, 0, 0);
        }
        __builtin_amdgcn_s_setprio(0);
    }

    // ---- combine key-halves (additive: no max tracking) ------------------
    float* PSm = (float*)Pw;
    if (l < 32) PSm[l] = lrow;                     // per-q partial sum
    BAR();
    if (kh == 1) {                                 // export partial O
        char* ex = smem + qg * 14336;
        #pragma unroll
        for (int h = 0; h < 2; ++h)
            #pragma unroll
            for (int dt = 0; dt < 7; ++dt)
                *(f4v*)(ex + ((h * 7 + dt) * 64 + l) * 16) = O[h][dt];
    }
    BAR();
    if (kh == 0) {
        const char* ex = smem + qg * 14336;
        #pragma unroll
        for (int h = 0; h < 2; ++h)
            #pragma unroll
            for (int dt = 0; dt < 7; ++dt)
                O[h][dt] += *(const f4v*)(ex + ((h * 7 + dt) * 64 + l) * 16);
        const float* PSp = (const float*)(smem + 61440 + (w + 4) * 2048);
        float linv[2][4];
        #pragma unroll
        for (int h = 0; h < 2; ++h)
            #pragma unroll
            for (int r = 0; r < 4; ++r) {
                int q = h * 16 + 4 * g + r;
                linv[h][r] = 1.f / (PSm[q] + PSp[q]);
            }
        if (l < 32) {
            long mb = (long)half * 32768 + b * 2048 + qt * 128 + qg * 32;
            ML[mb + l] = PSm[l] + PSp[l];
        }
        u16* vout = VOI + ((long)(half * 16 + b) * 2048 + qt * 128 + qg * 32) * 112;
        #pragma unroll
        for (int h = 0; h < 2; ++h) {
            #pragma unroll
            for (int r = 0; r < 4; ++r) {
                int row = h * 16 + 4 * g + r;
                #pragma unroll
                for (int dt = 0; dt < 7; ++dt)
                    vout[row * 112 + dt * 16 + c15] =
                        h2b((_Float16)(O[h][dt][r] * linv[h][r]));
            }
        }
    }
}

// ---------------- h = relu(VO@W2 + d1_b) via MFMA; fused half-combine ------
__global__ __launch_bounds__(256) void k_hpool(
    const u16* __restrict__ VOI, const float* __restrict__ ML,
    const u16* __restrict__ W2F, const float* __restrict__ d1b,
    float* __restrict__ pmax, float* __restrict__ psum) {
    __shared__ __align__(16) u16 A[8192];
    __shared__ float redM[4][400], redS[4][400];
    __shared__ float wgt[64][2];
    const int tid = threadIdx.x;
    const int w = tid >> 6, l = tid & 63, g = l >> 4, c15 = l & 15;
    const int b = blockIdx.y, rt = blockIdx.x;

    if (tid < 64) {
        float a = ML[b * 2048 + rt * 64 + tid];
        float c = ML[32768 + b * 2048 + rt * 64 + tid];
        float inv = 1.f / (a + c);
        wgt[tid][0] = a * inv;
        wgt[tid][1] = c * inv;
    }
    // zero-fill pad chunks c=14,15
    if (tid < 128) {
        int r = tid >> 1, c = 14 + (tid & 1);
        us8 z = {0, 0, 0, 0, 0, 0, 0, 0};
        *(us8*)&A[r * 128 + ((c * 8) ^ ((r & 7) << 3))] = z;
    }
    __syncthreads();

    const u16* s1 = VOI + ((long)b * 2048 + rt * 64) * 112;
    const u16* s2 = VOI + ((long)(16 + b) * 2048 + rt * 64) * 112;
    #pragma unroll
    for (int r = 0; r < 4; ++r) {
        int u = tid + r * 256;
        if (u < 896) {
            int row = u / 14, c = u % 14;
            us8 p1 = *(const us8*)&s1[row * 112 + c * 8];
            us8 p2 = *(const us8*)&s2[row * 112 + c * 8];
            float w1 = wgt[row][0], w2 = wgt[row][1];
            us8 o;
            #pragma unroll
            for (int j = 0; j < 8; ++j)
                o[j] = h2b((_Float16)(w1 * b2f(p1[j]) + w2 * b2f(p2[j])));
            *(us8*)&A[row * 128 + ((c * 8) ^ ((row & 7) << 3))] = o;
        }
    }
    __syncthreads();

    const int arow = w * 16 + c15;
    f16x8 af[4];
    #pragma unroll
    for (int ks = 0; ks < 4; ++ks)
        af[ks] = *(const f16x8*)&A[arow * 128 + ((ks * 32 + g * 8) ^ ((arow & 7) << 3))];

    for (int nt = 0; nt < 25; ++nt) {
        f4v acc = (f4v){0.f, 0.f, 0.f, 0.f};
        #pragma unroll
        for (int ks = 0; ks < 4; ++ks) {
            f16x8 bf = *(const f16x8*)&W2F[(nt * 4 + ks) * 512 + l * 8];
            acc = __builtin_amdgcn_mfma_f32_16x16x32_f16(af[ks], bf, acc, 0, 0, 0);
        }
        float bias = d1b[nt * 16 + c15];
        float mx4 = -1e30f, sm4 = 0.f;
        #pragma unroll
        for (int r = 0; r < 4; ++r) {
            float h = fmaxf(acc[r] + bias, 0.f);
            mx4 = fmaxf(mx4, h);
            sm4 += h;
        }
        mx4 = fmaxf(mx4, __shfl_xor(mx4, 16));
        mx4 = fmaxf(mx4, __shfl_xor(mx4, 32));
        sm4 += __shfl_xor(sm4, 16);
        sm4 += __shfl_xor(sm4, 32);
        if (g == 0) {
            redM[w][nt * 16 + c15] = mx4;
            redS[w][nt * 16 + c15] = sm4;
        }
    }
    __syncthreads();
    for (int j = tid; j < 400; j += 256) {
        float mx = fmaxf(fmaxf(redM[0][j], redM[1][j]), fmaxf(redM[2][j], redM[3][j]));
        float sm = redS[0][j] + redS[1][j] + redS[2][j] + redS[3][j];
        pmax[((long)b * 32 + rt) * 400 + j] = mx;
        psum[((long)b * 32 + rt) * 400 + j] = sm;
    }
}

// ---------------- pooled[b][800]: parallel t-slice reduce ------------------
__global__ __launch_bounds__(256) void k_pred(
    const float* __restrict__ pmax, const float* __restrict__ psum,
    float* __restrict__ pooled) {
    __shared__ float rm[16][17], rs[16][17];
    const int b = blockIdx.x, jt = blockIdx.y, tid = threadIdx.x;
    const int jo = tid & 15, ts = tid >> 4;
    const int j = jt * 16 + jo;
    float mx = -1e30f, sm = 0.f;
    for (int t = ts; t < 32; t += 16) {
        mx = fmaxf(mx, pmax[((long)b * 32 + t) * 400 + j]);
        sm += psum[((long)b * 32 + t) * 400 + j];
    }
    rm[ts][jo] = mx; rs[ts][jo] = sm;
    __syncthreads();
    if (tid < 16) {
        float m2 = rm[0][tid], s2 = rs[0][tid];
        #pragma unroll
        for (int t = 1; t < 16; ++t) { m2 = fmaxf(m2, rm[t][tid]); s2 += rs[t][tid]; }
        pooled[b * 800 + jt * 16 + tid] = m2;
        pooled[b * 800 + 400 + jt * 16 + tid] = s2 * (1.f / 2048.f);
    }
}

// ---------------- fc1: [16,800]x[800,512], k-split 16 ----------------------
__global__ __launch_bounds__(256) void k_fc1(
    const float* __restrict__ pooled, const float* __restrict__ w,
    const float* __restrict__ bias, float* __restrict__ out) {
    __shared__ float pl[800];
    __shared__ float red[16][17];
    const int b = blockIdx.x, jt = blockIdx.y, tid = threadIdx.x;
    const int jo = tid & 15, ks = tid >> 4;
    const int j = jt * 16 + jo;
    for (int i = tid; i < 800; i += 256) pl[i] = pooled[b * 800 + i];
    __syncthreads();
    float acc = 0.f;
    #pragma unroll 5
    for (int kk = 0; kk < 50; ++kk) {
        int k = ks * 50 + kk;
        acc += pl[k] * w[k * 512 + j];
    }
    red[ks][jo] = acc;
    __syncthreads();
    if (tid < 16) {
        float s = red[0][tid];
        #pragma unroll
        for (int t = 1; t < 16; ++t) s += red[t][tid];
        out[b * 512 + jt * 16 + tid] = fmaxf(s + bias[jt * 16 + tid], 0.f);
    }
}

// ---------------- fc2: [16,512]x[512,256], k-split 16 ----------------------
__global__ __launch_bounds__(256) void k_fc2(
    const float* __restrict__ h, const float* __restrict__ w,
    const float* __restrict__ bias, float* __restrict__ out) {
    __shared__ float hl[512];
    __shared__ float red[16][17];
    const int b = blockIdx.x, jt = blockIdx.y, tid = threadIdx.x;
    const int jo = tid & 15, ks = tid >> 4;
    const int j = jt * 16 + jo;
    for (int i = tid; i < 512; i += 256) hl[i] = h[b * 512 + i];
    __syncthreads();
    float acc = 0.f;
    #pragma unroll 4
    for (int kk = 0; kk < 32; ++kk) {
        int k = ks * 32 + kk;
        acc += hl[k] * w[k * 256 + j];
    }
    red[ks][jo] = acc;
    __syncthreads();
    if (tid < 16) {
        float s = red[0][tid];
        #pragma unroll
        for (int t = 1; t < 16; ++t) s += red[t][tid];
        out[b * 256 + jt * 16 + tid] = fmaxf(s + bias[jt * 16 + tid], 0.f);
    }
}

extern "C" void kernel_launch(void* const* d_in, const int* in_sizes, int n_in,
                              void* d_out, int out_size, void* d_ws, size_t ws_size,
                              hipStream_t stream) {
    const float* x          = (const float*)d_in[0];
    const float* attn_kernel= (const float*)d_in[1];
    const float* attn_dense = (const float*)d_in[2];
    const float* d1_w       = (const float*)d_in[3];
    const float* d1_b       = (const float*)d_in[4];
    const float* fc1_w      = (const float*)d_in[5];
    const float* fc1_b      = (const float*)d_in[6];
    const float* fc2_w      = (const float*)d_in[7];
    const float* fc2_b      = (const float*)d_in[8];
    float* out = (float*)d_out;
    char*  wsb = (char*)d_ws;

    // ws layout (bytes), total ~42.3 MB
    u16*    QH   = (u16*)(wsb);                    //  8,388,608
    u16*    KH   = (u16*)(wsb + 8388608);          //  8,388,608 (tile images)
    u16*    VT   = (u16*)(wsb + 16777216);         //  7,340,032 (packed tiles)
    u16*    VOI  = (u16*)(wsb + 24117248);         // 14,680,064 (2 packed halves)
    u16*    WSP  = (u16*)(wsb + 38797312);         //    638,976
    u16*    W2F  = (u16*)(wsb + 39436288);         //    102,400
    float*  PMAX = (float*)(wsb + 39538688);       //    819,200
    float*  PSUM = (float*)(wsb + 40357888);       //    819,200
    float*  ML   = (float*)(wsb + 41177088);       //    262,144
    float*  W2P  = (float*)(wsb + 41439232);       //    819,200
    float*  POOL = (float*)(wsb + 42258432);       //     51,200
    float*  FC1  = (float*)(wsb + 42309632);       //     32,768

    k_wprep<<<624, 256, 0, stream>>>(attn_kernel, WSP);
    k_w2p <<<dim3(200, 4), 256, 0, stream>>>(attn_dense, d1_w, W2P);
    k_w2r <<<200, 256, 0, stream>>>(W2P, W2F);
    k_gemm_qkv<<<256, 512, 0, stream>>>(x, WSP, QH, KH, VT);
    k_flash<<<dim3(16, 16, 2), 512, 0, stream>>>(QH, KH, VT, VOI, ML);
    k_hpool<<<dim3(32, 16), 256, 0, stream>>>(VOI, ML, W2F, d1_b, PMAX, PSUM);
    k_pred<<<dim3(16, 25), 256, 0, stream>>>(PMAX, PSUM, POOL);
    k_fc1 <<<dim3(16, 32), 256, 0, stream>>>(POOL, fc1_w, fc1_b, FC1);
    k_fc2 <<<dim3(16, 16), 256, 0, stream>>>(FC1, fc2_w, fc2_b, out);
}

// Round 17
// 137.501 us; speedup vs baseline: 1.0328x; 1.0328x over previous
//
#include <hip/hip_runtime.h>

typedef __attribute__((ext_vector_type(8))) _Float16 f16x8;
typedef __attribute__((ext_vector_type(4))) float f4v;
typedef __attribute__((ext_vector_type(8))) unsigned short us8;
typedef __attribute__((ext_vector_type(4))) unsigned short us4;
typedef unsigned short u16;

__device__ __forceinline__ u16 h2b(_Float16 h) { return __builtin_bit_cast(u16, h); }
__device__ __forceinline__ float b2f(u16 b) {
    return (float)__builtin_bit_cast(_Float16, b);
}

// Raw barrier: drain LDS ops only; leave prefetch global loads in flight.
#define BAR() do { asm volatile("s_waitcnt lgkmcnt(0)" ::: "memory"); \
                   __builtin_amdgcn_s_barrier(); } while (0)

// ---- W2 partials (fold fused): w2p[es][d][j] = sum_e adf[d][es*100+e]*d1w --
__global__ void k_w2p(const float* __restrict__ ad, const float* __restrict__ d1w,
                      float* __restrict__ w2p) {
    int i = blockIdx.x * 256 + threadIdx.x;       // 128 d x 400 j
    if (i >= 51200) return;
    int es = blockIdx.y;
    int d = i / 400, j = i % 400;
    float acc = 0.f;
    if (d < 100) {
        const float* a0 = ad + d * 400 + es * 100;          // + k*40000
        const float* wr = d1w + (es * 100) * 400 + j;
        #pragma unroll 4
        for (int e = 0; e < 100; ++e) {
            float av = a0[e] + a0[40000 + e] + a0[80000 + e] + a0[120000 + e];
            acc += av * wr[e * 400];
        }
    }
    w2p[es * 51200 + i] = acc;
}

// ---- reduce partials, pack to fp16 MFMA B-fragments [25 nt][4 ks][64][8] --
__global__ void k_w2r(const float* __restrict__ w2p, u16* __restrict__ w2f) {
    int i = blockIdx.x * 256 + threadIdx.x;
    if (i >= 51200) return;
    float acc = w2p[i] + w2p[51200 + i] + w2p[102400 + i] + w2p[153600 + i];
    int d = i / 400, j = i % 400;
    int idx = ((j >> 4) * 4 + (d >> 5)) * 512 + (((d >> 3) & 3) * 16 + (j & 15)) * 8 + (d & 7);
    w2f[idx] = h2b((_Float16)acc);
}

// ---- W prep: fp16 hi/lo tiles [3 m][13 ks][2 hl][128 n][32 k], x-swizzled -
__global__ void k_wprep(const float* __restrict__ ak, u16* __restrict__ wsp) {
    int i = blockIdx.x * 256 + threadIdx.x;       // 3*13*4096 = 159744
    if (i >= 159744) return;
    int k = i & 31, n = (i >> 5) & 127;
    int xx = i >> 12;                             // m*13 + ks
    int ks = xx % 13, m = xx / 13;
    int gk = ks * 32 + k;
    float v = (n < 100 && gk < 400) ? ak[m * 40000 + gk * 100 + n] : 0.f;
    _Float16 hb = (_Float16)v;
    _Float16 lb = (_Float16)(v - (float)hb);
    long base = (long)xx * 8192;
    int pos = n * 32 + ((((k >> 3) ^ (n & 3)) << 3) | (k & 7));
    wsp[base + pos] = h2b(hb);
    wsp[base + 4096 + pos] = h2b(lb);
}

// ---------------- QKV via fp16 MFMA: merged Q+K+V, BM=64, 8 waves ----------
// grid 512, block 512, 80KB LDS -> 2 blocks/CU (16 waves/CU).
// Waves: wm = w&3 row-tile (16 rows), wn = w>>2 N-half (4 nt each).
// Per-buf (u16): XH=0 XL=2048 QB=4096 KBH=8192 KBL=12288 VB=16384; str 20480.
__global__ __launch_bounds__(512) void k_gemm_qkv(
    const float* __restrict__ x, const u16* __restrict__ wsp,
    u16* __restrict__ QH, u16* __restrict__ KH, u16* __restrict__ VT) {
    __shared__ __align__(16) u16 smem[40960];     // 2 x 40KB; epi aliases

    const int tid = threadIdx.x;
    const int rowblk = blockIdx.x;
    const long row0 = (long)rowblk * 64;
    const int w = tid >> 6, l = tid & 63, g = l >> 4, c15 = l & 15;
    const int wm = w & 3, wn = w >> 2;
    const int sr = (tid & 255) >> 2, skc = tid & 3; // x-stage (tid<256 only)
    const bool xload = tid < 256;

    f4v aQ[4], aK[4], aV[4];
    #pragma unroll
    for (int j = 0; j < 4; ++j) {
        aQ[j] = (f4v){0.f, 0.f, 0.f, 0.f};
        aK[j] = (f4v){0.f, 0.f, 0.f, 0.f};
        aV[j] = (f4v){0.f, 0.f, 0.f, 0.f};
    }

    const u16* wq  = wsp;                          // m0 hi
    const u16* wkh = wsp + 106496;                 // m1 hi
    const u16* wkl = wsp + 110592;                 // m1 lo
    const u16* wv  = wsp + 212992;                 // m2 hi

    float4 xr0, xr1;
    us8 wr[4];
    const int xpos = sr * 32 + ((skc * 8) ^ ((sr & 3) << 3));

    // ---- prologue: load ks=0, stage into buf0, load ks=1
    {
        if (xload) {
            const float* xp = x + (row0 + sr) * 400 + skc * 8;
            xr0 = *(const float4*)xp;
            xr1 = *(const float4*)(xp + 4);
        }
        wr[0] = *(const us8*)&wq [(long)tid * 8];
        wr[1] = *(const us8*)&wkh[(long)tid * 8];
        wr[2] = *(const us8*)&wkl[(long)tid * 8];
        wr[3] = *(const us8*)&wv [(long)tid * 8];
        if (xload) {
            float va[8] = {xr0.x, xr0.y, xr0.z, xr0.w, xr1.x, xr1.y, xr1.z, xr1.w};
            us8 hi8, lo8;
            #pragma unroll
            for (int j = 0; j < 8; ++j) {
                _Float16 h = (_Float16)va[j];
                hi8[j] = h2b(h);
                lo8[j] = h2b((_Float16)(va[j] - (float)h));
            }
            *(us8*)&smem[xpos] = hi8;
            *(us8*)&smem[2048 + xpos] = lo8;
        }
        *(us8*)&smem[4096  + tid * 8] = wr[0];
        *(us8*)&smem[8192  + tid * 8] = wr[1];
        *(us8*)&smem[12288 + tid * 8] = wr[2];
        *(us8*)&smem[16384 + tid * 8] = wr[3];
        if (xload) {
            const float* xp1 = x + (row0 + sr) * 400 + 32 + skc * 8;
            xr0 = *(const float4*)xp1;
            xr1 = *(const float4*)(xp1 + 4);
        }
        wr[0] = *(const us8*)&wq [8192 + (long)tid * 8];
        wr[1] = *(const us8*)&wkh[8192 + (long)tid * 8];
        wr[2] = *(const us8*)&wkl[8192 + (long)tid * 8];
        wr[3] = *(const us8*)&wv [8192 + (long)tid * 8];
    }

    for (int ks = 0; ks < 13; ++ks) {
        BAR();
        u16* cb = smem + (ks & 1) * 20480;         // compute buf (tile ks)
        u16* sb = smem + ((ks & 1) ^ 1) * 20480;   // stage buf (tile ks+1)
        if (ks + 1 < 13) {
            if (xload) {
                float va[8] = {xr0.x, xr0.y, xr0.z, xr0.w, xr1.x, xr1.y, xr1.z, xr1.w};
                us8 hi8, lo8;
                #pragma unroll
                for (int j = 0; j < 8; ++j) {
                    _Float16 h = (_Float16)va[j];
                    hi8[j] = h2b(h);
                    lo8[j] = h2b((_Float16)(va[j] - (float)h));
                }
                *(us8*)&sb[xpos] = hi8;
                *(us8*)&sb[2048 + xpos] = lo8;
            }
            *(us8*)&sb[4096  + tid * 8] = wr[0];
            *(us8*)&sb[8192  + tid * 8] = wr[1];
            *(us8*)&sb[12288 + tid * 8] = wr[2];
            *(us8*)&sb[16384 + tid * 8] = wr[3];
            if (ks + 2 < 13) {
                if (xload) {
                    if ((ks + 2) * 32 + skc * 8 < 400) {
                        const float* xp = x + (row0 + sr) * 400 + (ks + 2) * 32 + skc * 8;
                        xr0 = *(const float4*)xp;
                        xr1 = *(const float4*)(xp + 4);
                    } else {
                        xr0 = make_float4(0.f, 0.f, 0.f, 0.f);
                        xr1 = make_float4(0.f, 0.f, 0.f, 0.f);
                    }
                }
                long wo = (long)(ks + 2) * 8192 + (long)tid * 8;
                wr[0] = *(const us8*)&wq [wo];
                wr[1] = *(const us8*)&wkh[wo];
                wr[2] = *(const us8*)&wkl[wo];
                wr[3] = *(const us8*)&wv [wo];
            }
        }
        // ---- MFMA on compute buf: wave (wm,wn): 16 rows x 4 nt x 7 MFMA
        const int arow = wm * 16 + c15;
        const int axo = arow * 32 + ((g * 8) ^ ((arow & 3) << 3));
        f16x8 ah = *(const f16x8*)&cb[axo];
        f16x8 al = *(const f16x8*)&cb[2048 + axo];
        __builtin_amdgcn_s_setprio(1);
        #pragma unroll
        for (int j = 0; j < 4; ++j) {
            int brow = (wn * 4 + j) * 16 + c15;
            int boff = brow * 32 + ((g * 8) ^ ((brow & 3) << 3));
            f16x8 qb = *(const f16x8*)&cb[4096 + boff];
            aQ[j] = __builtin_amdgcn_mfma_f32_16x16x32_f16(ah, qb, aQ[j], 0, 0, 0);
            aQ[j] = __builtin_amdgcn_mfma_f32_16x16x32_f16(al, qb, aQ[j], 0, 0, 0);
            f16x8 kh = *(const f16x8*)&cb[8192 + boff];
            aK[j] = __builtin_amdgcn_mfma_f32_16x16x32_f16(ah, kh, aK[j], 0, 0, 0);
            aK[j] = __builtin_amdgcn_mfma_f32_16x16x32_f16(al, kh, aK[j], 0, 0, 0);
            f16x8 kl = *(const f16x8*)&cb[12288 + boff];
            aK[j] = __builtin_amdgcn_mfma_f32_16x16x32_f16(ah, kl, aK[j], 0, 0, 0);
            f16x8 vb = *(const f16x8*)&cb[16384 + boff];
            aV[j] = __builtin_amdgcn_mfma_f32_16x16x32_f16(ah, vb, aV[j], 0, 0, 0);
            aV[j] = __builtin_amdgcn_mfma_f32_16x16x32_f16(al, vb, aV[j], 0, 0, 0);
        }
        __builtin_amdgcn_s_setprio(0);
    }
    BAR();
    u16* epi = smem;                               // alias (16KB, safe post-BAR)

    // ---- epilogue Q: swizzled deposit (scaled), un-swizzle to row-major
    {
        const float qs = 0.14426950408889634f;     // 0.1 * log2(e)
        #pragma unroll
        for (int j = 0; j < 4; ++j) {
            #pragma unroll
            for (int r = 0; r < 4; ++r) {
                int row = wm * 16 + 4 * g + r, col = (wn * 4 + j) * 16 + c15;
                epi[row * 128 + (col ^ ((row & 7) << 3))] =
                    h2b((_Float16)(aQ[j][r] * qs));
            }
        }
        __syncthreads();
        #pragma unroll
        for (int r = 0; r < 2; ++r) {
            int u = tid + r * 512;                 // 1024 us8 = 64 rows
            int row = u >> 4, c = u & 15;
            *(us8*)&QH[(row0 + row) * 128 + c * 8] =
                *(const us8*)&epi[row * 128 + ((c * 8) ^ ((row & 7) << 3))];
        }
        __syncthreads();
    }
    // ---- epilogue K: swizzled deposit, linear dump = 1 tile image
    {
        #pragma unroll
        for (int j = 0; j < 4; ++j) {
            #pragma unroll
            for (int r = 0; r < 4; ++r) {
                int row = wm * 16 + 4 * g + r, col = (wn * 4 + j) * 16 + c15;
                epi[row * 128 + (col ^ ((row & 7) << 3))] = h2b((_Float16)aK[j][r]);
            }
        }
        __syncthreads();
        u16* dst = KH + (long)rowblk * 8192;
        #pragma unroll
        for (int r = 0; r < 2; ++r) {
            int u = tid + r * 512;
            *(us8*)&dst[(long)u * 8] = *(const us8*)&epi[u * 8];
        }
        __syncthreads();
    }
    // ---- epilogue V: transposed deposit, dump 1 PACKED tile (d<112)
    {
        const int q0 = wm * 16 + 4 * g;            // 0..60
        #pragma unroll
        for (int j = 0; j < 4; ++j) {
            int d = (wn * 4 + j) * 16 + c15;
            if (d < 112) {
                us4 v4;
                #pragma unroll
                for (int r = 0; r < 4; ++r) v4[r] = h2b((_Float16)aV[j][r]);
                *(us4*)&epi[d * 64 + (q0 ^ ((d & 7) << 3))] = v4;
            }
        }
        __syncthreads();
        #pragma unroll
        for (int r = 0; r < 2; ++r) {
            int u = tid + r * 512;
            if (u < 896)
                *(us8*)&VT[(long)rowblk * 7168 + (long)u * 8] =
                    *(const us8*)&epi[u * 8];
        }
    }
}

// ---------------- fp16 MFMA flash: 128q x 8 waves, dbuf (proven r14, 53us) -
// grid (16, 16, 2), block 512. 1 barrier per KV tile; no-max softmax;
// reg-prefetch 2-deep pipeline (vmcnt never drained in loop).
__global__ __launch_bounds__(512) void k_flash(
    const u16* __restrict__ Qg, const u16* __restrict__ Kg,
    const u16* __restrict__ Vg, u16* __restrict__ VOI,
    float* __restrict__ ML) {
    __shared__ __align__(16) char KS[2][16384];  // K tile image [64r][16c]
    __shared__ __align__(16) char VS[2][14336];  // V^T tile image [112d][8c]
    __shared__ __align__(16) char PS[8][2048];   // per-wave P [16q][64k] (+l alias)

    const int tid = threadIdx.x;
    const int w = tid >> 6, l = tid & 63, g = l >> 4, c15 = l & 15;
    const int b = blockIdx.y, qt = blockIdx.x, half = blockIdx.z;
    const int t0 = half * 16;

    const u16* qp = Qg + ((long)b * 2048 + qt * 128 + w * 16 + c15) * 128;
    f16x8 qh[4];
    #pragma unroll
    for (int ks = 0; ks < 4; ++ks) qh[ks] = *(const f16x8*)(qp + ks * 32 + g * 8);

    f4v O[7];
    #pragma unroll
    for (int i = 0; i < 7; ++i) O[i] = (f4v){0.f, 0.f, 0.f, 0.f};
    float lrow = 0.f;

    const char* Kb = (const char*)(Kg + (long)b * 32 * 8192);   // 16384 B/tile
    const char* Vb = (const char*)(Vg + (long)b * 32 * 7168);   // 14336 B/tile
    char* Pw = PS[w];

    // ---- prologue: load t0 -> regs, write buf0, load t0+1 -> regs
    us8 kreg[2], vreg[2];
    #pragma unroll
    for (int r = 0; r < 2; ++r) {
        int u = tid + r * 512;
        kreg[r] = *(const us8*)(Kb + (long)t0 * 16384 + (long)u * 16);
        if (u < 896) vreg[r] = *(const us8*)(Vb + (long)t0 * 14336 + (long)u * 16);
    }
    #pragma unroll
    for (int r = 0; r < 2; ++r) {
        int u = tid + r * 512;
        *(us8*)(KS[0] + u * 16) = kreg[r];
        if (u < 896) *(us8*)(VS[0] + u * 16) = vreg[r];
    }
    #pragma unroll
    for (int r = 0; r < 2; ++r) {
        int u = tid + r * 512;
        kreg[r] = *(const us8*)(Kb + (long)(t0 + 1) * 16384 + (long)u * 16);
        if (u < 896) vreg[r] = *(const us8*)(Vb + (long)(t0 + 1) * 14336 + (long)u * 16);
    }

    for (int t = t0; t < t0 + 16; ++t) {
        const int cur = (t - t0) & 1;
        BAR();   // buf[cur] writes visible; buf[cur^1] readers (t-1) done
        if (t + 1 < t0 + 16) {
            #pragma unroll
            for (int r = 0; r < 2; ++r) {
                int u = tid + r * 512;
                *(us8*)(KS[cur ^ 1] + u * 16) = kreg[r];
                if (u < 896) *(us8*)(VS[cur ^ 1] + u * 16) = vreg[r];
            }
            if (t + 2 < t0 + 16) {
                #pragma unroll
                for (int r = 0; r < 2; ++r) {
                    int u = tid + r * 512;
                    kreg[r] = *(const us8*)(Kb + (long)(t + 2) * 16384 + (long)u * 16);
                    if (u < 896)
                        vreg[r] = *(const us8*)(Vb + (long)(t + 2) * 14336 + (long)u * 16);
                }
            }
        }
        const char* Kc = KS[cur];
        const char* Vc = VS[cur];

        // ---- S^T = K Q^T: lane (g,c15) reg (nt,r) = S[q=c15][key=16nt+4g+r]
        f4v s[4];
        #pragma unroll
        for (int nt = 0; nt < 4; ++nt) s[nt] = (f4v){0.f, 0.f, 0.f, 0.f};
        __builtin_amdgcn_s_setprio(1);
        #pragma unroll
        for (int ks = 0; ks < 4; ++ks) {
            #pragma unroll
            for (int nt = 0; nt < 4; ++nt) {
                int key = nt * 16 + c15;
                f16x8 kf = *(const f16x8*)(Kc + key * 256 +
                                           ((ks * 64 + g * 16) ^ ((key & 7) << 4)));
                s[nt] = __builtin_amdgcn_mfma_f32_16x16x32_f16(kf, qh[ks], s[nt], 0, 0, 0);
            }
        }
        __builtin_amdgcn_s_setprio(0);

        // ---- softmax numerators (logits bounded; Q pre-scaled by 0.1*log2e)
        float sum = 0.f;
        #pragma unroll
        for (int nt = 0; nt < 4; ++nt) {
            #pragma unroll
            for (int r = 0; r < 4; ++r) {
                float p = exp2f(s[nt][r]);
                s[nt][r] = p;
                sum += p;
            }
        }
        sum += __shfl_xor(sum, 16);
        sum += __shfl_xor(sum, 32);
        lrow += sum;

        // ---- P -> per-wave swizzled LDS (packed cvt_pkrtz pairs)
        #pragma unroll
        for (int nt = 0; nt < 4; ++nt) {
            uint2 pw2;
            pw2.x = __builtin_bit_cast(unsigned int,
                        __builtin_amdgcn_cvt_pkrtz(s[nt][0], s[nt][1]));
            pw2.y = __builtin_bit_cast(unsigned int,
                        __builtin_amdgcn_cvt_pkrtz(s[nt][2], s[nt][3]));
            *(uint2*)(Pw + c15 * 128 + ((32 * nt + 8 * g) ^ ((c15 & 7) << 4))) = pw2;
        }
        // ---- PV: O[16q][112d] += P[16q][64k] V[64k][d]
        __builtin_amdgcn_s_setprio(1);
        #pragma unroll
        for (int k0 = 0; k0 < 2; ++k0) {
            f16x8 pa = *(const f16x8*)(Pw + c15 * 128 +
                                       ((k0 * 64 + g * 16) ^ ((c15 & 7) << 4)));
            #pragma unroll
            for (int dt = 0; dt < 7; ++dt) {
                int d = dt * 16 + c15;
                f16x8 vf = *(const f16x8*)(Vc + d * 128 +
                                           ((k0 * 64 + g * 16) ^ ((d & 7) << 4)));
                O[dt] = __builtin_amdgcn_mfma_f32_16x16x32_f16(pa, vf, O[dt], 0, 0, 0);
            }
        }
        __builtin_amdgcn_s_setprio(0);
    }

    // ---- l-normalize + store PACKED fp16 partial image [.. rows][112 d] --
    if (g == 0) {
        ((float*)Pw)[c15] = lrow;
        ML[half * 32768 + b * 2048 + qt * 128 + w * 16 + c15] = lrow;
    }
    float linv[4];
    #pragma unroll
    for (int r = 0; r < 4; ++r) linv[r] = 1.f / ((float*)Pw)[4 * g + r];
    u16* vout = VOI + ((long)(half * 16 + b) * 2048 + qt * 128 + w * 16) * 112;
    #pragma unroll
    for (int r = 0; r < 4; ++r) {
        int row = 4 * g + r;
        #pragma unroll
        for (int dt = 0; dt < 7; ++dt)
            vout[row * 112 + dt * 16 + c15] =
                h2b((_Float16)(O[dt][r] * linv[r]));
    }
}

// ---------------- h = relu(VO@W2 + d1_b) via MFMA; fused half-combine ------
__global__ __launch_bounds__(256) void k_hpool(
    const u16* __restrict__ VOI, const float* __restrict__ ML,
    const u16* __restrict__ W2F, const float* __restrict__ d1b,
    float* __restrict__ pmax, float* __restrict__ psum) {
    __shared__ __align__(16) u16 A[8192];
    __shared__ float redM[4][400], redS[4][400];
    __shared__ float wgt[64][2];
    const int tid = threadIdx.x;
    const int w = tid >> 6, l = tid & 63, g = l >> 4, c15 = l & 15;
    const int b = blockIdx.y, rt = blockIdx.x;

    if (tid < 64) {
        float a = ML[b * 2048 + rt * 64 + tid];
        float c = ML[32768 + b * 2048 + rt * 64 + tid];
        float inv = 1.f / (a + c);
        wgt[tid][0] = a * inv;
        wgt[tid][1] = c * inv;
    }
    // zero-fill pad chunks c=14,15
    if (tid < 128) {
        int r = tid >> 1, c = 14 + (tid & 1);
        us8 z = {0, 0, 0, 0, 0, 0, 0, 0};
        *(us8*)&A[r * 128 + ((c * 8) ^ ((r & 7) << 3))] = z;
    }
    __syncthreads();

    const u16* s1 = VOI + ((long)b * 2048 + rt * 64) * 112;
    const u16* s2 = VOI + ((long)(16 + b) * 2048 + rt * 64) * 112;
    #pragma unroll
    for (int r = 0; r < 4; ++r) {
        int u = tid + r * 256;
        if (u < 896) {
            int row = u / 14, c = u % 14;
            us8 p1 = *(const us8*)&s1[row * 112 + c * 8];
            us8 p2 = *(const us8*)&s2[row * 112 + c * 8];
            float w1 = wgt[row][0], w2 = wgt[row][1];
            us8 o;
            #pragma unroll
            for (int j = 0; j < 8; ++j)
                o[j] = h2b((_Float16)(w1 * b2f(p1[j]) + w2 * b2f(p2[j])));
            *(us8*)&A[row * 128 + ((c * 8) ^ ((row & 7) << 3))] = o;
        }
    }
    __syncthreads();

    const int arow = w * 16 + c15;
    f16x8 af[4];
    #pragma unroll
    for (int ks = 0; ks < 4; ++ks)
        af[ks] = *(const f16x8*)&A[arow * 128 + ((ks * 32 + g * 8) ^ ((arow & 7) << 3))];

    for (int nt = 0; nt < 25; ++nt) {
        f4v acc = (f4v){0.f, 0.f, 0.f, 0.f};
        #pragma unroll
        for (int ks = 0; ks < 4; ++ks) {
            f16x8 bf = *(const f16x8*)&W2F[(nt * 4 + ks) * 512 + l * 8];
            acc = __builtin_amdgcn_mfma_f32_16x16x32_f16(af[ks], bf, acc, 0, 0, 0);
        }
        float bias = d1b[nt * 16 + c15];
        float mx4 = -1e30f, sm4 = 0.f;
        #pragma unroll
        for (int r = 0; r < 4; ++r) {
            float h = fmaxf(acc[r] + bias, 0.f);
            mx4 = fmaxf(mx4, h);
            sm4 += h;
        }
        mx4 = fmaxf(mx4, __shfl_xor(mx4, 16));
        mx4 = fmaxf(mx4, __shfl_xor(mx4, 32));
        sm4 += __shfl_xor(sm4, 16);
        sm4 += __shfl_xor(sm4, 32);
        if (g == 0) {
            redM[w][nt * 16 + c15] = mx4;
            redS[w][nt * 16 + c15] = sm4;
        }
    }
    __syncthreads();
    for (int j = tid; j < 400; j += 256) {
        float mx = fmaxf(fmaxf(redM[0][j], redM[1][j]), fmaxf(redM[2][j], redM[3][j]));
        float sm = redS[0][j] + redS[1][j] + redS[2][j] + redS[3][j];
        pmax[((long)b * 32 + rt) * 400 + j] = mx;
        psum[((long)b * 32 + rt) * 400 + j] = sm;
    }
}

// ---------------- pooled[b][800]: parallel t-slice reduce ------------------
__global__ __launch_bounds__(256) void k_pred(
    const float* __restrict__ pmax, const float* __restrict__ psum,
    float* __restrict__ pooled) {
    __shared__ float rm[16][17], rs[16][17];
    const int b = blockIdx.x, jt = blockIdx.y, tid = threadIdx.x;
    const int jo = tid & 15, ts = tid >> 4;
    const int j = jt * 16 + jo;
    float mx = -1e30f, sm = 0.f;
    for (int t = ts; t < 32; t += 16) {
        mx = fmaxf(mx, pmax[((long)b * 32 + t) * 400 + j]);
        sm += psum[((long)b * 32 + t) * 400 + j];
    }
    rm[ts][jo] = mx; rs[ts][jo] = sm;
    __syncthreads();
    if (tid < 16) {
        float m2 = rm[0][tid], s2 = rs[0][tid];
        #pragma unroll
        for (int t = 1; t < 16; ++t) { m2 = fmaxf(m2, rm[t][tid]); s2 += rs[t][tid]; }
        pooled[b * 800 + jt * 16 + tid] = m2;
        pooled[b * 800 + 400 + jt * 16 + tid] = s2 * (1.f / 2048.f);
    }
}

// ---------------- fc1: [16,800]x[800,512], k-split 16 ----------------------
__global__ __launch_bounds__(256) void k_fc1(
    const float* __restrict__ pooled, const float* __restrict__ w,
    const float* __restrict__ bias, float* __restrict__ out) {
    __shared__ float pl[800];
    __shared__ float red[16][17];
    const int b = blockIdx.x, jt = blockIdx.y, tid = threadIdx.x;
    const int jo = tid & 15, ks = tid >> 4;
    const int j = jt * 16 + jo;
    for (int i = tid; i < 800; i += 256) pl[i] = pooled[b * 800 + i];
    __syncthreads();
    float acc = 0.f;
    #pragma unroll 5
    for (int kk = 0; kk < 50; ++kk) {
        int k = ks * 50 + kk;
        acc += pl[k] * w[k * 512 + j];
    }
    red[ks][jo] = acc;
    __syncthreads();
    if (tid < 16) {
        float s = red[0][tid];
        #pragma unroll
        for (int t = 1; t < 16; ++t) s += red[t][tid];
        out[b * 512 + jt * 16 + tid] = fmaxf(s + bias[jt * 16 + tid], 0.f);
    }
}

// ---------------- fc2: [16,512]x[512,256], k-split 16 ----------------------
__global__ __launch_bounds__(256) void k_fc2(
    const float* __restrict__ h, const float* __restrict__ w,
    const float* __restrict__ bias, float* __restrict__ out) {
    __shared__ float hl[512];
    __shared__ float red[16][17];
    const int b = blockIdx.x, jt = blockIdx.y, tid = threadIdx.x;
    const int jo = tid & 15, ks = tid >> 4;
    const int j = jt * 16 + jo;
    for (int i = tid; i < 512; i += 256) hl[i] = h[b * 512 + i];
    __syncthreads();
    float acc = 0.f;
    #pragma unroll 4
    for (int kk = 0; kk < 32; ++kk) {
        int k = ks * 32 + kk;
        acc += hl[k] * w[k * 256 + j];
    }
    red[ks][jo] = acc;
    __syncthreads();
    if (tid < 16) {
        float s = red[0][tid];
        #pragma unroll
        for (int t = 1; t < 16; ++t) s += red[t][tid];
        out[b * 256 + jt * 16 + tid] = fmaxf(s + bias[jt * 16 + tid], 0.f);
    }
}

extern "C" void kernel_launch(void* const* d_in, const int* in_sizes, int n_in,
                              void* d_out, int out_size, void* d_ws, size_t ws_size,
                              hipStream_t stream) {
    const float* x          = (const float*)d_in[0];
    const float* attn_kernel= (const float*)d_in[1];
    const float* attn_dense = (const float*)d_in[2];
    const float* d1_w       = (const float*)d_in[3];
    const float* d1_b       = (const float*)d_in[4];
    const float* fc1_w      = (const float*)d_in[5];
    const float* fc1_b      = (const float*)d_in[6];
    const float* fc2_w      = (const float*)d_in[7];
    const float* fc2_b      = (const float*)d_in[8];
    float* out = (float*)d_out;
    char*  wsb = (char*)d_ws;

    // ws layout (bytes), total ~42.3 MB
    u16*    QH   = (u16*)(wsb);                    //  8,388,608
    u16*    KH   = (u16*)(wsb + 8388608);          //  8,388,608 (tile images)
    u16*    VT   = (u16*)(wsb + 16777216);         //  7,340,032 (packed tiles)
    u16*    VOI  = (u16*)(wsb + 24117248);         // 14,680,064 (2 packed halves)
    u16*    WSP  = (u16*)(wsb + 38797312);         //    638,976
    u16*    W2F  = (u16*)(wsb + 39436288);         //    102,400
    float*  PMAX = (float*)(wsb + 39538688);       //    819,200
    float*  PSUM = (float*)(wsb + 40357888);       //    819,200
    float*  ML   = (float*)(wsb + 41177088);       //    262,144
    float*  W2P  = (float*)(wsb + 41439232);       //    819,200
    float*  POOL = (float*)(wsb + 42258432);       //     51,200
    float*  FC1  = (float*)(wsb + 42309632);       //     32,768

    k_wprep<<<624, 256, 0, stream>>>(attn_kernel, WSP);
    k_w2p <<<dim3(200, 4), 256, 0, stream>>>(attn_dense, d1_w, W2P);
    k_w2r <<<200, 256, 0, stream>>>(W2P, W2F);
    k_gemm_qkv<<<512, 512, 0, stream>>>(x, WSP, QH, KH, VT);
    k_flash<<<dim3(16, 16, 2), 512, 0, stream>>>(QH, KH, VT, VOI, ML);
    k_hpool<<<dim3(32, 16), 256, 0, stream>>>(VOI, ML, W2F, d1_b, PMAX, PSUM);
    k_pred<<<dim3(16, 25), 256, 0, stream>>>(PMAX, PSUM, POOL);
    k_fc1 <<<dim3(16, 32), 256, 0, stream>>>(POOL, fc1_w, fc1_b, FC1);
    k_fc2 <<<dim3(16, 16), 256, 0, stream>>>(FC1, fc2_w, fc2_b, out);
}

// Round 18
// 129.599 us; speedup vs baseline: 1.0958x; 1.0610x over previous
//
#include <hip/hip_runtime.h>

typedef __attribute__((ext_vector_type(8))) _Float16 f16x8;
typedef __attribute__((ext_vector_type(4))) float f4v;
typedef __attribute__((ext_vector_type(8))) unsigned short us8;
typedef __attribute__((ext_vector_type(4))) unsigned short us4;
typedef unsigned short u16;

__device__ __forceinline__ u16 h2b(_Float16 h) { return __builtin_bit_cast(u16, h); }
__device__ __forceinline__ float b2f(u16 b) {
    return (float)__builtin_bit_cast(_Float16, b);
}

// Raw barrier: drain LDS ops only; leave prefetch global loads in flight.
#define BAR() do { asm volatile("s_waitcnt lgkmcnt(0)" ::: "memory"); \
                   __builtin_amdgcn_s_barrier(); } while (0)

// ---- merged prep: bx<624 -> W fp16 hi/lo tiles; bx>=624 -> W2 partials ----
// wprep: [3 m][13 ks][2 hl][128 n][32 k], x-swizzled.
// w2p (fold fused): w2p[es][d][j] = sum_e (sum_h ad[h][d][es*100+e]) * d1w.
__global__ void k_prep(const float* __restrict__ ak, u16* __restrict__ wsp,
                       const float* __restrict__ ad, const float* __restrict__ d1w,
                       float* __restrict__ w2p) {
    const int bx = blockIdx.x, tid = threadIdx.x;
    if (bx < 624) {
        int i = bx * 256 + tid;                   // 3*13*4096 = 159744
        if (i >= 159744) return;
        int k = i & 31, n = (i >> 5) & 127;
        int xx = i >> 12;                         // m*13 + ks
        int ks = xx % 13, m = xx / 13;
        int gk = ks * 32 + k;
        float v = (n < 100 && gk < 400) ? ak[m * 40000 + gk * 100 + n] : 0.f;
        _Float16 hb = (_Float16)v;
        _Float16 lb = (_Float16)(v - (float)hb);
        long base = (long)xx * 8192;
        int pos = n * 32 + ((((k >> 3) ^ (n & 3)) << 3) | (k & 7));
        wsp[base + pos] = h2b(hb);
        wsp[base + 4096 + pos] = h2b(lb);
    } else {
        int j2 = bx - 624;                        // 800 blocks: es = j2/200
        int es = j2 / 200;
        int i = (j2 % 200) * 256 + tid;           // 128 d x 400 j
        if (i >= 51200) return;
        int d = i / 400, j = i % 400;
        float acc = 0.f;
        if (d < 100) {
            const float* a0 = ad + d * 400 + es * 100;      // + k*40000
            const float* wr = d1w + (es * 100) * 400 + j;
            #pragma unroll 4
            for (int e = 0; e < 100; ++e) {
                float av = a0[e] + a0[40000 + e] + a0[80000 + e] + a0[120000 + e];
                acc += av * wr[e * 400];
            }
        }
        w2p[es * 51200 + i] = acc;
    }
}

// ---- reduce partials, pack to fp16 MFMA B-fragments [25 nt][4 ks][64][8] --
__global__ void k_w2r(const float* __restrict__ w2p, u16* __restrict__ w2f) {
    int i = blockIdx.x * 256 + threadIdx.x;
    if (i >= 51200) return;
    float acc = w2p[i] + w2p[51200 + i] + w2p[102400 + i] + w2p[153600 + i];
    int d = i / 400, j = i % 400;
    int idx = ((j >> 4) * 4 + (d >> 5)) * 512 + (((d >> 3) & 3) * 16 + (j & 15)) * 8 + (d & 7);
    w2f[idx] = h2b((_Float16)acc);
}

// ---------------- QKV via fp16 MFMA: merged Q+K+V, BM=64, 8 waves ----------
// grid 512, block 512, 64KB LDS -> 2 blocks/CU. 2-term Q/K/V: (xh+xl)*w_hi
// (K lo-weight term dropped: symmetric with Q's precision treatment).
// Per-buf (u16): XH=0 XL=2048 QB=4096 KB=8192 VB=12288; stride 16384.
__global__ __launch_bounds__(512) void k_gemm_qkv(
    const float* __restrict__ x, const u16* __restrict__ wsp,
    u16* __restrict__ QH, u16* __restrict__ KH, u16* __restrict__ VT) {
    __shared__ __align__(16) u16 smem[32768];     // 2 x 32KB; epi aliases

    const int tid = threadIdx.x;
    const int rowblk = blockIdx.x;
    const long row0 = (long)rowblk * 64;
    const int w = tid >> 6, l = tid & 63, g = l >> 4, c15 = l & 15;
    const int wm = w & 3, wn = w >> 2;
    const int sr = (tid & 255) >> 2, skc = tid & 3; // x-stage (tid<256 only)
    const bool xload = tid < 256;

    f4v aQ[4], aK[4], aV[4];
    #pragma unroll
    for (int j = 0; j < 4; ++j) {
        aQ[j] = (f4v){0.f, 0.f, 0.f, 0.f};
        aK[j] = (f4v){0.f, 0.f, 0.f, 0.f};
        aV[j] = (f4v){0.f, 0.f, 0.f, 0.f};
    }

    const u16* wq  = wsp;                          // m0 hi
    const u16* wkh = wsp + 106496;                 // m1 hi
    const u16* wv  = wsp + 212992;                 // m2 hi

    float4 xr0, xr1;
    us8 wr[3];
    const int xpos = sr * 32 + ((skc * 8) ^ ((sr & 3) << 3));

    // ---- prologue: load ks=0, stage into buf0, load ks=1
    {
        if (xload) {
            const float* xp = x + (row0 + sr) * 400 + skc * 8;
            xr0 = *(const float4*)xp;
            xr1 = *(const float4*)(xp + 4);
        }
        wr[0] = *(const us8*)&wq [(long)tid * 8];
        wr[1] = *(const us8*)&wkh[(long)tid * 8];
        wr[2] = *(const us8*)&wv [(long)tid * 8];
        if (xload) {
            float va[8] = {xr0.x, xr0.y, xr0.z, xr0.w, xr1.x, xr1.y, xr1.z, xr1.w};
            us8 hi8, lo8;
            #pragma unroll
            for (int j = 0; j < 8; ++j) {
                _Float16 h = (_Float16)va[j];
                hi8[j] = h2b(h);
                lo8[j] = h2b((_Float16)(va[j] - (float)h));
            }
            *(us8*)&smem[xpos] = hi8;
            *(us8*)&smem[2048 + xpos] = lo8;
        }
        *(us8*)&smem[4096  + tid * 8] = wr[0];
        *(us8*)&smem[8192  + tid * 8] = wr[1];
        *(us8*)&smem[12288 + tid * 8] = wr[2];
        if (xload) {
            const float* xp1 = x + (row0 + sr) * 400 + 32 + skc * 8;
            xr0 = *(const float4*)xp1;
            xr1 = *(const float4*)(xp1 + 4);
        }
        wr[0] = *(const us8*)&wq [8192 + (long)tid * 8];
        wr[1] = *(const us8*)&wkh[8192 + (long)tid * 8];
        wr[2] = *(const us8*)&wv [8192 + (long)tid * 8];
    }

    for (int ks = 0; ks < 13; ++ks) {
        BAR();
        u16* cb = smem + (ks & 1) * 16384;         // compute buf (tile ks)
        u16* sb = smem + ((ks & 1) ^ 1) * 16384;   // stage buf (tile ks+1)
        if (ks + 1 < 13) {
            if (xload) {
                float va[8] = {xr0.x, xr0.y, xr0.z, xr0.w, xr1.x, xr1.y, xr1.z, xr1.w};
                us8 hi8, lo8;
                #pragma unroll
                for (int j = 0; j < 8; ++j) {
                    _Float16 h = (_Float16)va[j];
                    hi8[j] = h2b(h);
                    lo8[j] = h2b((_Float16)(va[j] - (float)h));
                }
                *(us8*)&sb[xpos] = hi8;
                *(us8*)&sb[2048 + xpos] = lo8;
            }
            *(us8*)&sb[4096  + tid * 8] = wr[0];
            *(us8*)&sb[8192  + tid * 8] = wr[1];
            *(us8*)&sb[12288 + tid * 8] = wr[2];
            if (ks + 2 < 13) {
                if (xload) {
                    if ((ks + 2) * 32 + skc * 8 < 400) {
                        const float* xp = x + (row0 + sr) * 400 + (ks + 2) * 32 + skc * 8;
                        xr0 = *(const float4*)xp;
                        xr1 = *(const float4*)(xp + 4);
                    } else {
                        xr0 = make_float4(0.f, 0.f, 0.f, 0.f);
                        xr1 = make_float4(0.f, 0.f, 0.f, 0.f);
                    }
                }
                long wo = (long)(ks + 2) * 8192 + (long)tid * 8;
                wr[0] = *(const us8*)&wq [wo];
                wr[1] = *(const us8*)&wkh[wo];
                wr[2] = *(const us8*)&wv [wo];
            }
        }
        // ---- MFMA: wave (wm,wn): 16 rows x 4 nt x 6 MFMA
        const int arow = wm * 16 + c15;
        const int axo = arow * 32 + ((g * 8) ^ ((arow & 3) << 3));
        f16x8 ah = *(const f16x8*)&cb[axo];
        f16x8 al = *(const f16x8*)&cb[2048 + axo];
        __builtin_amdgcn_s_setprio(1);
        #pragma unroll
        for (int j = 0; j < 4; ++j) {
            int brow = (wn * 4 + j) * 16 + c15;
            int boff = brow * 32 + ((g * 8) ^ ((brow & 3) << 3));
            f16x8 qb = *(const f16x8*)&cb[4096 + boff];
            aQ[j] = __builtin_amdgcn_mfma_f32_16x16x32_f16(ah, qb, aQ[j], 0, 0, 0);
            aQ[j] = __builtin_amdgcn_mfma_f32_16x16x32_f16(al, qb, aQ[j], 0, 0, 0);
            f16x8 kh = *(const f16x8*)&cb[8192 + boff];
            aK[j] = __builtin_amdgcn_mfma_f32_16x16x32_f16(ah, kh, aK[j], 0, 0, 0);
            aK[j] = __builtin_amdgcn_mfma_f32_16x16x32_f16(al, kh, aK[j], 0, 0, 0);
            f16x8 vb = *(const f16x8*)&cb[12288 + boff];
            aV[j] = __builtin_amdgcn_mfma_f32_16x16x32_f16(ah, vb, aV[j], 0, 0, 0);
            aV[j] = __builtin_amdgcn_mfma_f32_16x16x32_f16(al, vb, aV[j], 0, 0, 0);
        }
        __builtin_amdgcn_s_setprio(0);
    }
    BAR();
    u16* epi = smem;                               // alias (16KB, safe post-BAR)

    // ---- epilogue Q: swizzled deposit (scaled), un-swizzle to row-major
    {
        const float qs = 0.14426950408889634f;     // 0.1 * log2(e)
        #pragma unroll
        for (int j = 0; j < 4; ++j) {
            #pragma unroll
            for (int r = 0; r < 4; ++r) {
                int row = wm * 16 + 4 * g + r, col = (wn * 4 + j) * 16 + c15;
                epi[row * 128 + (col ^ ((row & 7) << 3))] =
                    h2b((_Float16)(aQ[j][r] * qs));
            }
        }
        __syncthreads();
        #pragma unroll
        for (int r = 0; r < 2; ++r) {
            int u = tid + r * 512;                 // 1024 us8 = 64 rows
            int row = u >> 4, c = u & 15;
            *(us8*)&QH[(row0 + row) * 128 + c * 8] =
                *(const us8*)&epi[row * 128 + ((c * 8) ^ ((row & 7) << 3))];
        }
        __syncthreads();
    }
    // ---- epilogue K: swizzled deposit, linear dump = 1 tile image
    {
        #pragma unroll
        for (int j = 0; j < 4; ++j) {
            #pragma unroll
            for (int r = 0; r < 4; ++r) {
                int row = wm * 16 + 4 * g + r, col = (wn * 4 + j) * 16 + c15;
                epi[row * 128 + (col ^ ((row & 7) << 3))] = h2b((_Float16)aK[j][r]);
            }
        }
        __syncthreads();
        u16* dst = KH + (long)rowblk * 8192;
        #pragma unroll
        for (int r = 0; r < 2; ++r) {
            int u = tid + r * 512;
            *(us8*)&dst[(long)u * 8] = *(const us8*)&epi[u * 8];
        }
        __syncthreads();
    }
    // ---- epilogue V: transposed deposit, dump 1 PACKED tile (d<112)
    {
        const int q0 = wm * 16 + 4 * g;            // 0..60
        #pragma unroll
        for (int j = 0; j < 4; ++j) {
            int d = (wn * 4 + j) * 16 + c15;
            if (d < 112) {
                us4 v4;
                #pragma unroll
                for (int r = 0; r < 4; ++r) v4[r] = h2b((_Float16)aV[j][r]);
                *(us4*)&epi[d * 64 + (q0 ^ ((d & 7) << 3))] = v4;
            }
        }
        __syncthreads();
        #pragma unroll
        for (int r = 0; r < 2; ++r) {
            int u = tid + r * 512;
            if (u < 896)
                *(us8*)&VT[(long)rowblk * 7168 + (long)u * 8] =
                    *(const us8*)&epi[u * 8];
        }
    }
}

// ---------------- fp16 MFMA flash: 128q x 8 waves, dbuf (proven r14, 53us) -
// grid (16, 16, 2), block 512. 1 barrier per KV tile; no-max softmax;
// reg-prefetch 2-deep pipeline (vmcnt never drained in loop).
__global__ __launch_bounds__(512) void k_flash(
    const u16* __restrict__ Qg, const u16* __restrict__ Kg,
    const u16* __restrict__ Vg, u16* __restrict__ VOI,
    float* __restrict__ ML) {
    __shared__ __align__(16) char KS[2][16384];  // K tile image [64r][16c]
    __shared__ __align__(16) char VS[2][14336];  // V^T tile image [112d][8c]
    __shared__ __align__(16) char PS[8][2048];   // per-wave P [16q][64k] (+l alias)

    const int tid = threadIdx.x;
    const int w = tid >> 6, l = tid & 63, g = l >> 4, c15 = l & 15;
    const int b = blockIdx.y, qt = blockIdx.x, half = blockIdx.z;
    const int t0 = half * 16;

    const u16* qp = Qg + ((long)b * 2048 + qt * 128 + w * 16 + c15) * 128;
    f16x8 qh[4];
    #pragma unroll
    for (int ks = 0; ks < 4; ++ks) qh[ks] = *(const f16x8*)(qp + ks * 32 + g * 8);

    f4v O[7];
    #pragma unroll
    for (int i = 0; i < 7; ++i) O[i] = (f4v){0.f, 0.f, 0.f, 0.f};
    float lrow = 0.f;

    const char* Kb = (const char*)(Kg + (long)b * 32 * 8192);   // 16384 B/tile
    const char* Vb = (const char*)(Vg + (long)b * 32 * 7168);   // 14336 B/tile
    char* Pw = PS[w];

    // ---- prologue: load t0 -> regs, write buf0, load t0+1 -> regs
    us8 kreg[2], vreg[2];
    #pragma unroll
    for (int r = 0; r < 2; ++r) {
        int u = tid + r * 512;
        kreg[r] = *(const us8*)(Kb + (long)t0 * 16384 + (long)u * 16);
        if (u < 896) vreg[r] = *(const us8*)(Vb + (long)t0 * 14336 + (long)u * 16);
    }
    #pragma unroll
    for (int r = 0; r < 2; ++r) {
        int u = tid + r * 512;
        *(us8*)(KS[0] + u * 16) = kreg[r];
        if (u < 896) *(us8*)(VS[0] + u * 16) = vreg[r];
    }
    #pragma unroll
    for (int r = 0; r < 2; ++r) {
        int u = tid + r * 512;
        kreg[r] = *(const us8*)(Kb + (long)(t0 + 1) * 16384 + (long)u * 16);
        if (u < 896) vreg[r] = *(const us8*)(Vb + (long)(t0 + 1) * 14336 + (long)u * 16);
    }

    for (int t = t0; t < t0 + 16; ++t) {
        const int cur = (t - t0) & 1;
        BAR();   // buf[cur] writes visible; buf[cur^1] readers (t-1) done
        if (t + 1 < t0 + 16) {
            #pragma unroll
            for (int r = 0; r < 2; ++r) {
                int u = tid + r * 512;
                *(us8*)(KS[cur ^ 1] + u * 16) = kreg[r];
                if (u < 896) *(us8*)(VS[cur ^ 1] + u * 16) = vreg[r];
            }
            if (t + 2 < t0 + 16) {
                #pragma unroll
                for (int r = 0; r < 2; ++r) {
                    int u = tid + r * 512;
                    kreg[r] = *(const us8*)(Kb + (long)(t + 2) * 16384 + (long)u * 16);
                    if (u < 896)
                        vreg[r] = *(const us8*)(Vb + (long)(t + 2) * 14336 + (long)u * 16);
                }
            }
        }
        const char* Kc = KS[cur];
        const char* Vc = VS[cur];

        // ---- S^T = K Q^T: lane (g,c15) reg (nt,r) = S[q=c15][key=16nt+4g+r]
        f4v s[4];
        #pragma unroll
        for (int nt = 0; nt < 4; ++nt) s[nt] = (f4v){0.f, 0.f, 0.f, 0.f};
        __builtin_amdgcn_s_setprio(1);
        #pragma unroll
        for (int ks = 0; ks < 4; ++ks) {
            #pragma unroll
            for (int nt = 0; nt < 4; ++nt) {
                int key = nt * 16 + c15;
                f16x8 kf = *(const f16x8*)(Kc + key * 256 +
                                           ((ks * 64 + g * 16) ^ ((key & 7) << 4)));
                s[nt] = __builtin_amdgcn_mfma_f32_16x16x32_f16(kf, qh[ks], s[nt], 0, 0, 0);
            }
        }
        __builtin_amdgcn_s_setprio(0);

        // ---- softmax numerators (logits bounded; Q pre-scaled by 0.1*log2e)
        float sum = 0.f;
        #pragma unroll
        for (int nt = 0; nt < 4; ++nt) {
            #pragma unroll
            for (int r = 0; r < 4; ++r) {
                float p = exp2f(s[nt][r]);
                s[nt][r] = p;
                sum += p;
            }
        }
        sum += __shfl_xor(sum, 16);
        sum += __shfl_xor(sum, 32);
        lrow += sum;

        // ---- P -> per-wave swizzled LDS (packed cvt_pkrtz pairs)
        #pragma unroll
        for (int nt = 0; nt < 4; ++nt) {
            uint2 pw2;
            pw2.x = __builtin_bit_cast(unsigned int,
                        __builtin_amdgcn_cvt_pkrtz(s[nt][0], s[nt][1]));
            pw2.y = __builtin_bit_cast(unsigned int,
                        __builtin_amdgcn_cvt_pkrtz(s[nt][2], s[nt][3]));
            *(uint2*)(Pw + c15 * 128 + ((32 * nt + 8 * g) ^ ((c15 & 7) << 4))) = pw2;
        }
        // ---- PV: O[16q][112d] += P[16q][64k] V[64k][d]
        __builtin_amdgcn_s_setprio(1);
        #pragma unroll
        for (int k0 = 0; k0 < 2; ++k0) {
            f16x8 pa = *(const f16x8*)(Pw + c15 * 128 +
                                       ((k0 * 64 + g * 16) ^ ((c15 & 7) << 4)));
            #pragma unroll
            for (int dt = 0; dt < 7; ++dt) {
                int d = dt * 16 + c15;
                f16x8 vf = *(const f16x8*)(Vc + d * 128 +
                                           ((k0 * 64 + g * 16) ^ ((d & 7) << 4)));
                O[dt] = __builtin_amdgcn_mfma_f32_16x16x32_f16(pa, vf, O[dt], 0, 0, 0);
            }
        }
        __builtin_amdgcn_s_setprio(0);
    }

    // ---- l-normalize + store PACKED fp16 partial image [.. rows][112 d] --
    if (g == 0) {
        ((float*)Pw)[c15] = lrow;
        ML[half * 32768 + b * 2048 + qt * 128 + w * 16 + c15] = lrow;
    }
    float linv[4];
    #pragma unroll
    for (int r = 0; r < 4; ++r) linv[r] = 1.f / ((float*)Pw)[4 * g + r];
    u16* vout = VOI + ((long)(half * 16 + b) * 2048 + qt * 128 + w * 16) * 112;
    #pragma unroll
    for (int r = 0; r < 4; ++r) {
        int row = 4 * g + r;
        #pragma unroll
        for (int dt = 0; dt < 7; ++dt)
            vout[row * 112 + dt * 16 + c15] =
                h2b((_Float16)(O[dt][r] * linv[r]));
    }
}

// ---------------- h = relu(VO@W2 + d1_b) via MFMA; fused half-combine ------
__global__ __launch_bounds__(256) void k_hpool(
    const u16* __restrict__ VOI, const float* __restrict__ ML,
    const u16* __restrict__ W2F, const float* __restrict__ d1b,
    float* __restrict__ pmax, float* __restrict__ psum) {
    __shared__ __align__(16) u16 A[8192];
    __shared__ float redM[4][400], redS[4][400];
    __shared__ float wgt[64][2];
    const int tid = threadIdx.x;
    const int w = tid >> 6, l = tid & 63, g = l >> 4, c15 = l & 15;
    const int b = blockIdx.y, rt = blockIdx.x;

    if (tid < 64) {
        float a = ML[b * 2048 + rt * 64 + tid];
        float c = ML[32768 + b * 2048 + rt * 64 + tid];
        float inv = 1.f / (a + c);
        wgt[tid][0] = a * inv;
        wgt[tid][1] = c * inv;
    }
    // zero-fill pad chunks c=14,15
    if (tid < 128) {
        int r = tid >> 1, c = 14 + (tid & 1);
        us8 z = {0, 0, 0, 0, 0, 0, 0, 0};
        *(us8*)&A[r * 128 + ((c * 8) ^ ((r & 7) << 3))] = z;
    }
    __syncthreads();

    const u16* s1 = VOI + ((long)b * 2048 + rt * 64) * 112;
    const u16* s2 = VOI + ((long)(16 + b) * 2048 + rt * 64) * 112;
    #pragma unroll
    for (int r = 0; r < 4; ++r) {
        int u = tid + r * 256;
        if (u < 896) {
            int row = u / 14, c = u % 14;
            us8 p1 = *(const us8*)&s1[row * 112 + c * 8];
            us8 p2 = *(const us8*)&s2[row * 112 + c * 8];
            float w1 = wgt[row][0], w2 = wgt[row][1];
            us8 o;
            #pragma unroll
            for (int j = 0; j < 8; ++j)
                o[j] = h2b((_Float16)(w1 * b2f(p1[j]) + w2 * b2f(p2[j])));
            *(us8*)&A[row * 128 + ((c * 8) ^ ((row & 7) << 3))] = o;
        }
    }
    __syncthreads();

    const int arow = w * 16 + c15;
    f16x8 af[4];
    #pragma unroll
    for (int ks = 0; ks < 4; ++ks)
        af[ks] = *(const f16x8*)&A[arow * 128 + ((ks * 32 + g * 8) ^ ((arow & 7) << 3))];

    for (int nt = 0; nt < 25; ++nt) {
        f4v acc = (f4v){0.f, 0.f, 0.f, 0.f};
        #pragma unroll
        for (int ks = 0; ks < 4; ++ks) {
            f16x8 bf = *(const f16x8*)&W2F[(nt * 4 + ks) * 512 + l * 8];
            acc = __builtin_amdgcn_mfma_f32_16x16x32_f16(af[ks], bf, acc, 0, 0, 0);
        }
        float bias = d1b[nt * 16 + c15];
        float mx4 = -1e30f, sm4 = 0.f;
        #pragma unroll
        for (int r = 0; r < 4; ++r) {
            float h = fmaxf(acc[r] + bias, 0.f);
            mx4 = fmaxf(mx4, h);
            sm4 += h;
        }
        mx4 = fmaxf(mx4, __shfl_xor(mx4, 16));
        mx4 = fmaxf(mx4, __shfl_xor(mx4, 32));
        sm4 += __shfl_xor(sm4, 16);
        sm4 += __shfl_xor(sm4, 32);
        if (g == 0) {
            redM[w][nt * 16 + c15] = mx4;
            redS[w][nt * 16 + c15] = sm4;
        }
    }
    __syncthreads();
    for (int j = tid; j < 400; j += 256) {
        float mx = fmaxf(fmaxf(redM[0][j], redM[1][j]), fmaxf(redM[2][j], redM[3][j]));
        float sm = redS[0][j] + redS[1][j] + redS[2][j] + redS[3][j];
        pmax[((long)b * 32 + rt) * 400 + j] = mx;
        psum[((long)b * 32 + rt) * 400 + j] = sm;
    }
}

// ---------------- pooled[b][800]: parallel t-slice reduce ------------------
__global__ __launch_bounds__(256) void k_pred(
    const float* __restrict__ pmax, const float* __restrict__ psum,
    float* __restrict__ pooled) {
    __shared__ float rm[16][17], rs[16][17];
    const int b = blockIdx.x, jt = blockIdx.y, tid = threadIdx.x;
    const int jo = tid & 15, ts = tid >> 4;
    const int j = jt * 16 + jo;
    float mx = -1e30f, sm = 0.f;
    for (int t = ts; t < 32; t += 16) {
        mx = fmaxf(mx, pmax[((long)b * 32 + t) * 400 + j]);
        sm += psum[((long)b * 32 + t) * 400 + j];
    }
    rm[ts][jo] = mx; rs[ts][jo] = sm;
    __syncthreads();
    if (tid < 16) {
        float m2 = rm[0][tid], s2 = rs[0][tid];
        #pragma unroll
        for (int t = 1; t < 16; ++t) { m2 = fmaxf(m2, rm[t][tid]); s2 += rs[t][tid]; }
        pooled[b * 800 + jt * 16 + tid] = m2;
        pooled[b * 800 + 400 + jt * 16 + tid] = s2 * (1.f / 2048.f);
    }
}

// ---------------- fc1: [16,800]x[800,512], k-split 16 ----------------------
__global__ __launch_bounds__(256) void k_fc1(
    const float* __restrict__ pooled, const float* __restrict__ w,
    const float* __restrict__ bias, float* __restrict__ out) {
    __shared__ float pl[800];
    __shared__ float red[16][17];
    const int b = blockIdx.x, jt = blockIdx.y, tid = threadIdx.x;
    const int jo = tid & 15, ks = tid >> 4;
    const int j = jt * 16 + jo;
    for (int i = tid; i < 800; i += 256) pl[i] = pooled[b * 800 + i];
    __syncthreads();
    float acc = 0.f;
    #pragma unroll 5
    for (int kk = 0; kk < 50; ++kk) {
        int k = ks * 50 + kk;
        acc += pl[k] * w[k * 512 + j];
    }
    red[ks][jo] = acc;
    __syncthreads();
    if (tid < 16) {
        float s = red[0][tid];
        #pragma unroll
        for (int t = 1; t < 16; ++t) s += red[t][tid];
        out[b * 512 + jt * 16 + tid] = fmaxf(s + bias[jt * 16 + tid], 0.f);
    }
}

// ---------------- fc2: [16,512]x[512,256], k-split 16 ----------------------
__global__ __launch_bounds__(256) void k_fc2(
    const float* __restrict__ h, const float* __restrict__ w,
    const float* __restrict__ bias, float* __restrict__ out) {
    __shared__ float hl[512];
    __shared__ float red[16][17];
    const int b = blockIdx.x, jt = blockIdx.y, tid = threadIdx.x;
    const int jo = tid & 15, ks = tid >> 4;
    const int j = jt * 16 + jo;
    for (int i = tid; i < 512; i += 256) hl[i] = h[b * 512 + i];
    __syncthreads();
    float acc = 0.f;
    #pragma unroll 4
    for (int kk = 0; kk < 32; ++kk) {
        int k = ks * 32 + kk;
        acc += hl[k] * w[k * 256 + j];
    }
    red[ks][jo] = acc;
    __syncthreads();
    if (tid < 16) {
        float s = red[0][tid];
        #pragma unroll
        for (int t = 1; t < 16; ++t) s += red[t][tid];
        out[b * 256 + jt * 16 + tid] = fmaxf(s + bias[jt * 16 + tid], 0.f);
    }
}

extern "C" void kernel_launch(void* const* d_in, const int* in_sizes, int n_in,
                              void* d_out, int out_size, void* d_ws, size_t ws_size,
                              hipStream_t stream) {
    const float* x          = (const float*)d_in[0];
    const float* attn_kernel= (const float*)d_in[1];
    const float* attn_dense = (const float*)d_in[2];
    const float* d1_w       = (const float*)d_in[3];
    const float* d1_b       = (const float*)d_in[4];
    const float* fc1_w      = (const float*)d_in[5];
    const float* fc1_b      = (const float*)d_in[6];
    const float* fc2_w      = (const float*)d_in[7];
    const float* fc2_b      = (const float*)d_in[8];
    float* out = (float*)d_out;
    char*  wsb = (char*)d_ws;

    // ws layout (bytes), total ~42.3 MB
    u16*    QH   = (u16*)(wsb);                    //  8,388,608
    u16*    KH   = (u16*)(wsb + 8388608);          //  8,388,608 (tile images)
    u16*    VT   = (u16*)(wsb + 16777216);         //  7,340,032 (packed tiles)
    u16*    VOI  = (u16*)(wsb + 24117248);         // 14,680,064 (2 packed halves)
    u16*    WSP  = (u16*)(wsb + 38797312);         //    638,976
    u16*    W2F  = (u16*)(wsb + 39436288);         //    102,400
    float*  PMAX = (float*)(wsb + 39538688);       //    819,200
    float*  PSUM = (float*)(wsb + 40357888);       //    819,200
    float*  ML   = (float*)(wsb + 41177088);       //    262,144
    float*  W2P  = (float*)(wsb + 41439232);       //    819,200
    float*  POOL = (float*)(wsb + 42258432);       //     51,200
    float*  FC1  = (float*)(wsb + 42309632);       //     32,768

    k_prep<<<1424, 256, 0, stream>>>(attn_kernel, WSP, attn_dense, d1_w, W2P);
    k_w2r <<<200, 256, 0, stream>>>(W2P, W2F);
    k_gemm_qkv<<<512, 512, 0, stream>>>(x, WSP, QH, KH, VT);
    k_flash<<<dim3(16, 16, 2), 512, 0, stream>>>(QH, KH, VT, VOI, ML);
    k_hpool<<<dim3(32, 16), 256, 0, stream>>>(VOI, ML, W2F, d1_b, PMAX, PSUM);
    k_pred<<<dim3(16, 25), 256, 0, stream>>>(PMAX, PSUM, POOL);
    k_fc1 <<<dim3(16, 32), 256, 0, stream>>>(POOL, fc1_w, fc1_b, FC1);
    k_fc2 <<<dim3(16, 16), 256, 0, stream>>>(FC1, fc2_w, fc2_b, out);
}